// Round 13
// baseline (213.304 us; speedup 1.0000x reference)
//
#include <hip/hip_runtime.h>
#include <math.h>

#define D 64
#define K 512

typedef __attribute__((ext_vector_type(8))) short short8;
typedef __attribute__((ext_vector_type(4))) float f32x4;

// ---------- workspace layout (256-aligned) ----------
// 0       : int cnt               (legacy slot, written by pack_prep)
// 256     : float e2[512]         (np-exact, read by inline rescan)
// 2304    : float sq[512]         (np-exact, read by inline rescan)
// 4352    : float2 ets[512]       ({e2*sq + BIAS, 2*sq}, global reads in loop)
// 8448    : ushort Bp[65536]      (bf16 splits, per-t frag-contiguous, 128KB)
// 1188096 : double partial[256]   (screen per-block loss)
#define WS_E2    256
#define WS_SQ    2304
#define WS_ETS   4352
#define WS_BP    8448
#define WS_PART  1188096

#define KEYMASK 0xFFFFFE00u   // drop 9 mantissa bits, keep 9 index bits
#define DIST_BIAS 0.0625f     // uniform shift: argmin/gap invariant, keeps dist>0

__device__ __forceinline__ unsigned short f32_to_bf16_rne(float f)
{
    unsigned int u = __float_as_uint(f);
    unsigned int r = (u + 0x7FFFu + ((u >> 16) & 1u)) >> 16;
    return (unsigned short)r;
}
__device__ __forceinline__ float bf16_to_f32(unsigned short h)
{
    return __uint_as_float(((unsigned int)h) << 16);
}

// numpy pairwise sum of v[i]*v[i], n=64 — exact numpy algorithm
__device__ __forceinline__ float np_sumsq64(const float* v)
{
#pragma clang fp contract(off)
    float p[64];
#pragma unroll
    for (int i = 0; i < 64; ++i) p[i] = v[i] * v[i];
    float r[8];
#pragma unroll
    for (int j = 0; j < 8; ++j) r[j] = p[j];
#pragma unroll
    for (int b = 8; b < 64; b += 8) {
#pragma unroll
        for (int j = 0; j < 8; ++j) r[j] += p[b + j];
    }
    return ((r[0] + r[1]) + (r[2] + r[3])) + ((r[4] + r[5]) + (r[6] + r[7]));
}

// ---------------------------------------------------------------------------
// Kernel 1: pack codebook bf16 splits, frag-contiguous per t-step
// (byte-identical to the R7/R10/R12-passed version).
// ---------------------------------------------------------------------------
__global__ __launch_bounds__(256) void vq_pack_prep(
    const float* __restrict__ emb,
    const float* __restrict__ cs,
    unsigned short* __restrict__ Bp,
    float* __restrict__ e2,
    float* __restrict__ sq,
    float2* __restrict__ ets,
    int* __restrict__ cnt)
{
    int i = blockIdx.x * blockDim.x + threadIdx.x;
    if (i < 65536) {
        int j    = i & 7;
        int lane = (i >> 3) & 63;
        int frag = (i >> 9) & 3;
        int t    = (i >> 11) & 31;
        int kc   = frag & 1;
        int sB   = frag >> 1;
        int code = t * 16 + (lane & 15);
        int d    = kc * 32 + (lane >> 4) * 8 + j;
        float v = emb[code * 64 + d];
        unsigned short b0 = f32_to_bf16_rne(v);
        Bp[i] = (sB == 0) ? b0 : f32_to_bf16_rne(v - bf16_to_f32(b0));
    } else if (i < 66048) {
        int k = i - 65536;
        float er[64];
        const float* ek = emb + (size_t)k * D;
#pragma unroll
        for (int d = 0; d < 64; ++d) er[d] = ek[d];
        float e2v = np_sumsq64(er);
        float sqv = (float)sqrt((double)cs[k]);
        e2[k] = e2v;
        sq[k] = sqv;
        ets[k] = make_float2(e2v * sqv + DIST_BIAS, 2.0f * sqv);
    } else if (i == 66048) {
        *cnt = 0;
    }
}

// ---------------------------------------------------------------------------
// Noinline rescan: np-exact argmin for this block's flagged points.
// Isolated from the screen function so its row[64] register array and tail
// live-ranges do NOT perturb the main loop's register allocation/scheduling
// (R12 post-mortem: inlining this tail cost the main loop +47% with
// identical counters). Ops are verbatim the R9-proven vq_exact core with
// global e2/sq tables — bit-identical dist, unique lexicographic argmin.
// Returns this wave's fp64 loss contribution (nonzero on lane 0 only).
// ---------------------------------------------------------------------------
__device__ __attribute__((noinline)) double vq_rescan(
    const float* __restrict__ x,
    const float* __restrict__ emb,
    const float* __restrict__ e2,
    const float* __restrict__ sq,
    const int* lwl, int nf, int wave, int lane,
    float* __restrict__ out_idx,
    float* __restrict__ out_q)
{
    double acc_s = 0.0;
    for (int w = wave; w < nf; w += 8) {
        int p = lwl[w];
        const float* xrow = x + (size_t)p * 64;
        float row[64];
#pragma unroll
        for (int i = 0; i < 16; ++i) {
            float4 v = ((const float4*)xrow)[i];
            row[4 * i + 0] = v.x; row[4 * i + 1] = v.y;
            row[4 * i + 2] = v.z; row[4 * i + 3] = v.w;
        }
        float x2 = np_sumsq64(row);

        float bd = INFINITY;
        int   bc = 0;
        for (int t = 0; t < 8; ++t) {
            int c = t * 64 + lane;
            const float* er = emb + (size_t)c * 64;
            float acc = 0.0f;
#pragma unroll
            for (int d = 0; d < 64; ++d)
                acc = fmaf(row[d], er[d], acc);
            float dist;
            {
#pragma clang fp contract(off)
                dist = ((x2 + e2[c]) - 2.0f * acc) * sq[c];
            }
            if (dist < bd) { bd = dist; bc = c; }
        }
#pragma unroll
        for (int wd = 1; wd < 64; wd <<= 1) {
            float od = __shfl_xor(bd, wd, 64);
            int   oc = __shfl_xor(bc, wd, 64);
            if (od < bd || (od == bd && oc < bc)) { bd = od; bc = oc; }
        }
        if (lane == 0) out_idx[p] = (float)bc;

        float xv = x[(size_t)p * 64 + lane];
        float qv = emb[(size_t)bc * 64 + lane];
        float t, o;
        {
#pragma clang fp contract(off)
            t = qv - xv;
            o = xv + t;
        }
        out_q[(size_t)p * 64 + lane] = o;
        double dd = (double)t * (double)t;
#pragma unroll
        for (int off = 32; off > 0; off >>= 1)
            dd += __shfl_down(dd, off, 64);
        if (lane == 0) acc_s += dd;
    }
    return acc_s;
}

// ---------------------------------------------------------------------------
// Kernel 2: R7-proven CU-resident-codebook MFMA screen + fused epilogue +
// noinline rescan call. Main loop is byte-identical to R7 (ets from GLOBAL,
// no extra LDS tables); only additions vs R7 are the 4KB LDS worklist and
// the post-loop call. 256 blocks (1/CU) x 512 threads, 2 passes x 4 rt.
// ---------------------------------------------------------------------------
__global__ __launch_bounds__(512) void vq_screen(
    const float* __restrict__ x,
    const float* __restrict__ emb,
    const float* __restrict__ e2,
    const float* __restrict__ sq,
    const float2* __restrict__ ets,
    const unsigned short* __restrict__ Bp,
    float* __restrict__ out_q,
    float* __restrict__ out_idx,
    double* __restrict__ partial)
{
    __shared__ unsigned short BpS[65536];   // 128 KB: full codebook, both terms
    __shared__ int    lwl[1024];            // per-block flagged worklist
    __shared__ int    lcnt;
    __shared__ double ls[8];

    const int wave = threadIdx.x >> 6;      // 0..7
    const int lane = threadIdx.x & 63;
    const int quad = lane >> 4;
    const int n16  = lane & 15;

    // ---- stage full packed codebook once: 8192 float4, 16 per thread ----
    {
        const float4* src = (const float4*)Bp;
        float4* dst = (float4*)BpS;
#pragma unroll
        for (int it = 0; it < 16; ++it)
            dst[threadIdx.x + it * 512] = src[threadIdx.x + it * 512];
    }
    if (threadIdx.x == 0) lcnt = 0;
    __syncthreads();

    double s = 0.0;

    for (int pass = 0; pass < 2; ++pass) {
        const int n0 = blockIdx.x * 1024 + pass * 512 + wave * 64;

        // ---- A fragments (bf16 2-term split, RNE) + negated half-x2 ----
        short8 A0[4][2], A1[4][2];
        f32x4 negx2h[4];
#pragma unroll
        for (int rt = 0; rt < 4; ++rt) {
            float sx = 0.0f;
#pragma unroll
            for (int kc = 0; kc < 2; ++kc) {
                const float* src = x + (size_t)(n0 + rt * 16 + n16) * 64
                                   + kc * 32 + quad * 8;
                float4 v0 = *(const float4*)(src);
                float4 v1 = *(const float4*)(src + 4);
                float xv[8] = {v0.x, v0.y, v0.z, v0.w, v1.x, v1.y, v1.z, v1.w};
#pragma unroll
                for (int j = 0; j < 8; ++j) {
                    float v = xv[j];
                    unsigned short b0 = f32_to_bf16_rne(v);
                    unsigned short b1 = f32_to_bf16_rne(v - bf16_to_f32(b0));
                    A0[rt][kc][j] = (short)b0;
                    A1[rt][kc][j] = (short)b1;
                    sx = fmaf(v, v, sx);
                }
            }
            sx += __shfl_xor(sx, 16, 64);
            sx += __shfl_xor(sx, 32, 64);
            // acc[r] belongs to point quad*4+r (m89 C/D layout) -> its -x2/2
#pragma unroll
            for (int r = 0; r < 4; ++r)
                negx2h[rt][r] = -0.5f * __shfl(sx, quad * 4 + r, 64);
        }

        unsigned k1[4][4], k2[4][4];
#pragma unroll
        for (int rt = 0; rt < 4; ++rt)
#pragma unroll
            for (int r = 0; r < 4; ++r) { k1[rt][r] = 0xFFFFFFFFu; k2[rt][r] = 0xFFFFFFFFu; }

        // ---- main loop: 32 t-steps, B from LDS, ets from GLOBAL (R7 form) ----
#pragma unroll 2
        for (int t = 0; t < 32; ++t) {
            const unsigned short* bp = BpS + t * 2048 + lane * 8;
            const short8 B00 = *(const short8*)(bp);           // sB0,kc0
            const short8 B01 = *(const short8*)(bp + 512);     // sB0,kc1
            const short8 B10 = *(const short8*)(bp + 1024);    // sB1,kc0
            const short8 B11 = *(const short8*)(bp + 1536);    // sB1,kc1
            float2 et = ets[t * 16 + n16];                     // {e2sq+BIAS, 2sq}
            unsigned cbits = (unsigned)(t * 16 + n16);

#pragma unroll
            for (int rt = 0; rt < 4; ++rt) {
                f32x4 acc = negx2h[rt];
                acc = __builtin_amdgcn_mfma_f32_16x16x32_bf16(A0[rt][0], B00, acc, 0, 0, 0);
                acc = __builtin_amdgcn_mfma_f32_16x16x32_bf16(A0[rt][1], B01, acc, 0, 0, 0);
                acc = __builtin_amdgcn_mfma_f32_16x16x32_bf16(A0[rt][0], B10, acc, 0, 0, 0);
                acc = __builtin_amdgcn_mfma_f32_16x16x32_bf16(A0[rt][1], B11, acc, 0, 0, 0);
                acc = __builtin_amdgcn_mfma_f32_16x16x32_bf16(A1[rt][0], B00, acc, 0, 0, 0);
                acc = __builtin_amdgcn_mfma_f32_16x16x32_bf16(A1[rt][1], B01, acc, 0, 0, 0);

#pragma unroll
                for (int r = 0; r < 4; ++r) {
                    // acc = x.e - x2/2  ->  dist = e2sq+BIAS - tsq*acc
                    float dist = fmaf(-et.y, acc[r], et.x);
                    unsigned key = (__float_as_uint(dist) & KEYMASK) | cbits;
                    unsigned a1 = k1[rt][r];
                    unsigned a2;
                    asm("v_med3_u32 %0, %1, %2, %3"
                        : "=v"(a2) : "v"(a1), "v"(k2[rt][r]), "v"(key));
                    k2[rt][r] = a2;
                    k1[rt][r] = a1 < key ? a1 : key;
                }
            }
        }

        // merge best-2 across the 16 lanes of each quad (uint keys)
#pragma unroll
        for (int rt = 0; rt < 4; ++rt)
#pragma unroll
            for (int r = 0; r < 4; ++r) {
                unsigned a1 = k1[rt][r], a2 = k2[rt][r];
#pragma unroll
                for (int w = 1; w < 16; w <<= 1) {
                    unsigned o1 = (unsigned)__shfl_xor((int)a1, w, 64);
                    unsigned o2 = (unsigned)__shfl_xor((int)a2, w, 64);
                    unsigned mx  = a1 > o1 ? a1 : o1;
                    a1 = a1 < o1 ? a1 : o1;
                    unsigned mn2 = a2 < o2 ? a2 : o2;
                    a2 = mn2 < mx ? mn2 : mx;
                }
                k1[rt][r] = a1; k2[rt][r] = a2;
            }

        // flags, provisional index writes, per-block LDS worklist
        unsigned pk[4][4];
#pragma unroll
        for (int rt = 0; rt < 4; ++rt)
#pragma unroll
            for (int r = 0; r < 4; ++r) {
                float d1f = __uint_as_float(k1[rt][r] & KEYMASK);
                float d2f = __uint_as_float(k2[rt][r] & KEYMASK);
                int   i1  = (int)(k1[rt][r] & 0x1FFu);
                int   flg = (d2f - d1f) <= (0.01f + 2.0e-4f * d2f);
                pk[rt][r] = (unsigned)i1 | (flg ? 0x8000u : 0u);
                if (n16 == 0) {
                    int p = n0 + rt * 16 + quad * 4 + r;
                    out_idx[p] = (float)i1;
                    if (flg) { int slot = atomicAdd(&lcnt, 1); lwl[slot] = p; }
                }
            }

        // fused epilogue for certified points: broadcast (bi,flag) to the 4
        // lanes holding each point's x-slice, gather, STE, fp64 loss
        int src = (n16 >> 2) * 16 + n16;  // any lane of quad n16>>2 has the merge
#pragma unroll
        for (int rt = 0; rt < 4; ++rt) {
            unsigned p0 = (unsigned)__shfl((int)pk[rt][0], src, 64);
            unsigned p1 = (unsigned)__shfl((int)pk[rt][1], src, 64);
            unsigned p2 = (unsigned)__shfl((int)pk[rt][2], src, 64);
            unsigned p3 = (unsigned)__shfl((int)pk[rt][3], src, 64);
            int rr = n16 & 3;
            unsigned pm = (rr == 0) ? p0 : (rr == 1) ? p1 : (rr == 2) ? p2 : p3;
            int bim = (int)(pm & 0x1FFu);
            int flg = (int)((pm >> 15) & 1u);
            if (!flg) {
                int prow = n0 + rt * 16 + n16;
#pragma unroll
                for (int kc = 0; kc < 2; ++kc) {
                    const float* xs = x   + (size_t)prow * 64 + kc * 32 + quad * 8;
                    const float* es = emb + (size_t)bim  * 64 + kc * 32 + quad * 8;
                    float4 xv0 = *(const float4*)(xs);
                    float4 xv1 = *(const float4*)(xs + 4);
                    float4 ev0 = *(const float4*)(es);
                    float4 ev1 = *(const float4*)(es + 4);
                    float4 o0, o1;
                    float t0, t1, t2, t3, t4, t5, t6, t7;
                    {
#pragma clang fp contract(off)
                        t0 = ev0.x - xv0.x; o0.x = xv0.x + t0;
                        t1 = ev0.y - xv0.y; o0.y = xv0.y + t1;
                        t2 = ev0.z - xv0.z; o0.z = xv0.z + t2;
                        t3 = ev0.w - xv0.w; o0.w = xv0.w + t3;
                        t4 = ev1.x - xv1.x; o1.x = xv1.x + t4;
                        t5 = ev1.y - xv1.y; o1.y = xv1.y + t5;
                        t6 = ev1.z - xv1.z; o1.z = xv1.z + t6;
                        t7 = ev1.w - xv1.w; o1.w = xv1.w + t7;
                    }
                    float* od = out_q + (size_t)prow * 64 + kc * 32 + quad * 8;
                    *(float4*)(od)     = o0;
                    *(float4*)(od + 4) = o1;
                    s += (double)t0 * t0 + (double)t1 * t1
                       + (double)t2 * t2 + (double)t3 * t3
                       + (double)t4 * t4 + (double)t5 * t5
                       + (double)t6 * t6 + (double)t7 * t7;
                }
            }
        }
    }

    // ---- noinline rescan of this block's flagged points ----
    __syncthreads();
    {
        const int nf = lcnt;
        if (nf > 0)
            s += vq_rescan(x, emb, e2, sq, lwl, nf, wave, lane,
                           out_idx, out_q);
    }

    // ---- per-block loss partial ----
#pragma unroll
    for (int off = 32; off > 0; off >>= 1)
        s += __shfl_down(s, off, 64);
    if (lane == 0) ls[wave] = s;
    __syncthreads();
    if (threadIdx.x == 0)
        partial[blockIdx.x] = ls[0] + ls[1] + ls[2] + ls[3]
                            + ls[4] + ls[5] + ls[6] + ls[7];
}

// ---------------------------------------------------------------------------
// Kernel 3: reduce per-block partials -> loss
// ---------------------------------------------------------------------------
__global__ __launch_bounds__(256) void vq_finalize(
    const double* __restrict__ partial,
    float* __restrict__ loss_out,
    int nblk, double inv_count)
{
    double s = 0.0;
    for (int i = threadIdx.x; i < nblk; i += 256) s += partial[i];
#pragma unroll
    for (int off = 32; off > 0; off >>= 1)
        s += __shfl_down(s, off, 64);
    __shared__ double ls[4];
    if ((threadIdx.x & 63) == 0) ls[threadIdx.x >> 6] = s;
    __syncthreads();
    if (threadIdx.x == 0) {
        double total = ls[0] + ls[1] + ls[2] + ls[3];
        loss_out[0] = (float)(0.25 * total * inv_count);
    }
}

// ---------------------------------------------------------------------------
extern "C" void kernel_launch(void* const* d_in, const int* in_sizes, int n_in,
                              void* d_out, int out_size, void* d_ws, size_t ws_size,
                              hipStream_t stream)
{
    const float* x   = (const float*)d_in[0];   // [N, 64]
    const float* emb = (const float*)d_in[1];   // [512, 64]
    const float* cs  = (const float*)d_in[2];   // [512]

    const int N = in_sizes[0] / D;              // 262144

    float* out      = (float*)d_out;
    float* out_q    = out;                      // [N*64]
    float* out_loss = out + (size_t)N * D;      // [1]
    float* out_idx  = out_loss + 1;             // [N]

    char* ws = (char*)d_ws;
    int*            cnt     = (int*)ws;
    float*          e2      = (float*)(ws + WS_E2);
    float*          sq      = (float*)(ws + WS_SQ);
    float2*         ets     = (float2*)(ws + WS_ETS);
    unsigned short* Bp      = (unsigned short*)(ws + WS_BP);
    double*         partial = (double*)(ws + WS_PART);

    const int nblk_screen = N / 1024;           // 256 blocks = 1/CU

    vq_pack_prep<<<259, 256, 0, stream>>>(emb, cs, Bp, e2, sq, ets, cnt);
    vq_screen<<<nblk_screen, 512, 0, stream>>>(x, emb, e2, sq, ets, Bp,
                                               out_q, out_idx, partial);
    vq_finalize<<<1, 256, 0, stream>>>(partial, out_loss, nblk_screen,
                                       1.0 / ((double)N * (double)D));
}

// Round 14
// 203.737 us; speedup vs baseline: 1.0470x; 1.0470x over previous
//
#include <hip/hip_runtime.h>
#include <math.h>

#define D 64
#define K 512

typedef __attribute__((ext_vector_type(8))) short short8;
typedef __attribute__((ext_vector_type(4))) float f32x4;

// ---------- workspace layout (256-aligned) ----------
// 0       : int cnt
// 256     : float e2[512]           (np-exact, for vq_exact)
// 2304    : float sq[512]           (np-exact, for vq_exact)
// 4352    : float2 ets[512]         ({e2*sq + BIAS, 2*sq}, screen only)
// 8448    : ushort Bp[65536]        (bf16 splits, per-t frag-contiguous, 128KB)
// 139520  : int wl[N]               (1MB)
// 1188096 : double partial[2048]    (screen per-block loss; 256 used)
// 1204480 : double partial2[N]      (exact per-flagged-point loss)
#define WS_E2    256
#define WS_SQ    2304
#define WS_ETS   4352
#define WS_BP    8448
#define WS_WL    139520
#define WS_PART  1188096
#define WS_PART2 1204480

#define KEYMASK 0xFFFFFE00u   // drop 9 mantissa bits, keep 9 index bits
#define DIST_BIAS 0.0625f     // uniform shift: argmin/gap invariant, keeps dist>0

__device__ __forceinline__ unsigned short f32_to_bf16_rne(float f)
{
    unsigned int u = __float_as_uint(f);
    unsigned int r = (u + 0x7FFFu + ((u >> 16) & 1u)) >> 16;
    return (unsigned short)r;
}
__device__ __forceinline__ float bf16_to_f32(unsigned short h)
{
    return __uint_as_float(((unsigned int)h) << 16);
}

// numpy pairwise sum of v[i]*v[i], n=64 — exact numpy algorithm
__device__ __forceinline__ float np_sumsq64(const float* v)
{
#pragma clang fp contract(off)
    float p[64];
#pragma unroll
    for (int i = 0; i < 64; ++i) p[i] = v[i] * v[i];
    float r[8];
#pragma unroll
    for (int j = 0; j < 8; ++j) r[j] = p[j];
#pragma unroll
    for (int b = 8; b < 64; b += 8) {
#pragma unroll
        for (int j = 0; j < 8; ++j) r[j] += p[b + j];
    }
    return ((r[0] + r[1]) + (r[2] + r[3])) + ((r[4] + r[5]) + (r[6] + r[7]));
}

// ---------------------------------------------------------------------------
// Kernel 1: pack codebook bf16 splits, frag-contiguous per t-step:
// element i = t<<11 | frag<<9 | lane<<3 | j    (frag = sB*2 + kc)
//   code = t*16 + (lane&15); d = kc*32 + (lane>>4)*8 + j
// Also: np-exact e2/sq for vq_exact; float2 ets = {e2*sq+BIAS, 2*sq} for the
// screen; zero worklist counter.  (Byte-identical to the R4/R7-passed version.)
// ---------------------------------------------------------------------------
__global__ __launch_bounds__(256) void vq_pack_prep(
    const float* __restrict__ emb,
    const float* __restrict__ cs,
    unsigned short* __restrict__ Bp,
    float* __restrict__ e2,
    float* __restrict__ sq,
    float2* __restrict__ ets,
    int* __restrict__ cnt)
{
    int i = blockIdx.x * blockDim.x + threadIdx.x;
    if (i < 65536) {
        int j    = i & 7;
        int lane = (i >> 3) & 63;
        int frag = (i >> 9) & 3;
        int t    = (i >> 11) & 31;
        int kc   = frag & 1;
        int sB   = frag >> 1;
        int code = t * 16 + (lane & 15);
        int d    = kc * 32 + (lane >> 4) * 8 + j;
        float v = emb[code * 64 + d];
        unsigned short b0 = f32_to_bf16_rne(v);
        Bp[i] = (sB == 0) ? b0 : f32_to_bf16_rne(v - bf16_to_f32(b0));
    } else if (i < 66048) {
        int k = i - 65536;
        float er[64];
        const float* ek = emb + (size_t)k * D;
#pragma unroll
        for (int d = 0; d < 64; ++d) er[d] = ek[d];
        float e2v = np_sumsq64(er);
        float sqv = (float)sqrt((double)cs[k]);
        e2[k] = e2v;
        sq[k] = sqv;
        ets[k] = make_float2(e2v * sqv + DIST_BIAS, 2.0f * sqv);
    } else if (i == 66048) {
        *cnt = 0;
    }
}

// ---------------------------------------------------------------------------
// Kernel 2: CU-resident-codebook MFMA screen + fused epilogue (R4 pipeline)
// with ONE change vs R4: 4 rt per wave (64 points) instead of 2.
// 256 blocks (1/CU) x 512 threads, 2 passes x 8 waves x 64 points.
// Per t-step: 4 independent 6-MFMA chains (4-way ILP to cover MFMA dep
// latency + ds_read latency at 2 waves/SIMD) and the same 4 ds_read + 1
// ets load amortized over 2x the points. R5 ablation showed the main loop
// alone is ~70us and latency-bound — this attacks exactly that.
// ---------------------------------------------------------------------------
__global__ __launch_bounds__(512) void vq_screen(
    const float* __restrict__ x,
    const float* __restrict__ emb,
    const float2* __restrict__ ets,
    const unsigned short* __restrict__ Bp,
    float* __restrict__ out_q,
    float* __restrict__ out_idx,
    int* __restrict__ wl,
    int* __restrict__ cnt,
    double* __restrict__ partial)
{
    __shared__ unsigned short BpS[65536];   // 128 KB: full codebook, both terms
    __shared__ double ls[8];

    const int wave = threadIdx.x >> 6;      // 0..7
    const int lane = threadIdx.x & 63;
    const int quad = lane >> 4;
    const int n16  = lane & 15;

    // ---- stage full packed codebook once: 8192 float4, 16 per thread ----
    {
        const float4* src = (const float4*)Bp;
        float4* dst = (float4*)BpS;
#pragma unroll
        for (int it = 0; it < 16; ++it)
            dst[threadIdx.x + it * 512] = src[threadIdx.x + it * 512];
    }
    __syncthreads();

    double s = 0.0;

    for (int pass = 0; pass < 2; ++pass) {
        const int n0 = blockIdx.x * 1024 + pass * 512 + wave * 64;

        // ---- A fragments (bf16 2-term split, RNE) + negated half-x2 ----
        short8 A0[4][2], A1[4][2];
        f32x4 negx2h[4];
#pragma unroll
        for (int rt = 0; rt < 4; ++rt) {
            float sx = 0.0f;
#pragma unroll
            for (int kc = 0; kc < 2; ++kc) {
                const float* src = x + (size_t)(n0 + rt * 16 + n16) * 64
                                   + kc * 32 + quad * 8;
                float4 v0 = *(const float4*)(src);
                float4 v1 = *(const float4*)(src + 4);
                float xv[8] = {v0.x, v0.y, v0.z, v0.w, v1.x, v1.y, v1.z, v1.w};
#pragma unroll
                for (int j = 0; j < 8; ++j) {
                    float v = xv[j];
                    unsigned short b0 = f32_to_bf16_rne(v);
                    unsigned short b1 = f32_to_bf16_rne(v - bf16_to_f32(b0));
                    A0[rt][kc][j] = (short)b0;
                    A1[rt][kc][j] = (short)b1;
                    sx = fmaf(v, v, sx);
                }
            }
            sx += __shfl_xor(sx, 16, 64);
            sx += __shfl_xor(sx, 32, 64);
            // acc[r] belongs to point quad*4+r (m89 C/D layout) -> its -x2/2
#pragma unroll
            for (int r = 0; r < 4; ++r)
                negx2h[rt][r] = -0.5f * __shfl(sx, quad * 4 + r, 64);
        }

        unsigned k1[4][4], k2[4][4];
#pragma unroll
        for (int rt = 0; rt < 4; ++rt)
#pragma unroll
            for (int r = 0; r < 4; ++r) { k1[rt][r] = 0xFFFFFFFFu; k2[rt][r] = 0xFFFFFFFFu; }

        // ---- main loop: 32 t-steps, B from LDS, no barriers ----
#pragma unroll 2
        for (int t = 0; t < 32; ++t) {
            const unsigned short* bp = BpS + t * 2048 + lane * 8;
            const short8 B00 = *(const short8*)(bp);           // sB0,kc0
            const short8 B01 = *(const short8*)(bp + 512);     // sB0,kc1
            const short8 B10 = *(const short8*)(bp + 1024);    // sB1,kc0
            const short8 B11 = *(const short8*)(bp + 1536);    // sB1,kc1
            float2 et = ets[t * 16 + n16];                     // {e2sq+BIAS, 2sq}
            unsigned cbits = (unsigned)(t * 16 + n16);

#pragma unroll
            for (int rt = 0; rt < 4; ++rt) {
                f32x4 acc = negx2h[rt];
                acc = __builtin_amdgcn_mfma_f32_16x16x32_bf16(A0[rt][0], B00, acc, 0, 0, 0);
                acc = __builtin_amdgcn_mfma_f32_16x16x32_bf16(A0[rt][1], B01, acc, 0, 0, 0);
                acc = __builtin_amdgcn_mfma_f32_16x16x32_bf16(A0[rt][0], B10, acc, 0, 0, 0);
                acc = __builtin_amdgcn_mfma_f32_16x16x32_bf16(A0[rt][1], B11, acc, 0, 0, 0);
                acc = __builtin_amdgcn_mfma_f32_16x16x32_bf16(A1[rt][0], B00, acc, 0, 0, 0);
                acc = __builtin_amdgcn_mfma_f32_16x16x32_bf16(A1[rt][1], B01, acc, 0, 0, 0);

#pragma unroll
                for (int r = 0; r < 4; ++r) {
                    // acc = x.e - x2/2  ->  dist = e2sq+BIAS - tsq*acc
                    float dist = fmaf(-et.y, acc[r], et.x);
                    unsigned key = (__float_as_uint(dist) & KEYMASK) | cbits;
                    unsigned a1 = k1[rt][r];
                    unsigned a2;
                    asm("v_med3_u32 %0, %1, %2, %3"
                        : "=v"(a2) : "v"(a1), "v"(k2[rt][r]), "v"(key));
                    k2[rt][r] = a2;
                    k1[rt][r] = a1 < key ? a1 : key;
                }
            }
        }

        // merge best-2 across the 16 lanes of each quad (uint keys)
#pragma unroll
        for (int rt = 0; rt < 4; ++rt)
#pragma unroll
            for (int r = 0; r < 4; ++r) {
                unsigned a1 = k1[rt][r], a2 = k2[rt][r];
#pragma unroll
                for (int w = 1; w < 16; w <<= 1) {
                    unsigned o1 = (unsigned)__shfl_xor((int)a1, w, 64);
                    unsigned o2 = (unsigned)__shfl_xor((int)a2, w, 64);
                    unsigned mx  = a1 > o1 ? a1 : o1;
                    a1 = a1 < o1 ? a1 : o1;
                    unsigned mn2 = a2 < o2 ? a2 : o2;
                    a2 = mn2 < mx ? mn2 : mx;
                }
                k1[rt][r] = a1; k2[rt][r] = a2;
            }

        // flags, index writes, worklist
        unsigned pk[4][4];
#pragma unroll
        for (int rt = 0; rt < 4; ++rt)
#pragma unroll
            for (int r = 0; r < 4; ++r) {
                float d1f = __uint_as_float(k1[rt][r] & KEYMASK);
                float d2f = __uint_as_float(k2[rt][r] & KEYMASK);
                int   i1  = (int)(k1[rt][r] & 0x1FFu);
                int   flg = (d2f - d1f) <= (0.01f + 2.0e-4f * d2f);
                pk[rt][r] = (unsigned)i1 | (flg ? 0x8000u : 0u);
                if (n16 == 0) {
                    int p = n0 + rt * 16 + quad * 4 + r;
                    out_idx[p] = (float)i1;
                    if (flg) { int slot = atomicAdd(cnt, 1); wl[slot] = p; }
                }
            }

        // fused epilogue for certified points: broadcast (bi,flag) to the 4
        // lanes holding each point's x-slice, gather, STE, fp64 loss
        int src = (n16 >> 2) * 16 + n16;  // any lane of quad n16>>2 has the merge
#pragma unroll
        for (int rt = 0; rt < 4; ++rt) {
            unsigned p0 = (unsigned)__shfl((int)pk[rt][0], src, 64);
            unsigned p1 = (unsigned)__shfl((int)pk[rt][1], src, 64);
            unsigned p2 = (unsigned)__shfl((int)pk[rt][2], src, 64);
            unsigned p3 = (unsigned)__shfl((int)pk[rt][3], src, 64);
            int rr = n16 & 3;
            unsigned pm = (rr == 0) ? p0 : (rr == 1) ? p1 : (rr == 2) ? p2 : p3;
            int bim = (int)(pm & 0x1FFu);
            int flg = (int)((pm >> 15) & 1u);
            if (!flg) {
                int prow = n0 + rt * 16 + n16;
#pragma unroll
                for (int kc = 0; kc < 2; ++kc) {
                    const float* xs = x   + (size_t)prow * 64 + kc * 32 + quad * 8;
                    const float* es = emb + (size_t)bim  * 64 + kc * 32 + quad * 8;
                    float4 xv0 = *(const float4*)(xs);
                    float4 xv1 = *(const float4*)(xs + 4);
                    float4 ev0 = *(const float4*)(es);
                    float4 ev1 = *(const float4*)(es + 4);
                    float4 o0, o1;
                    float t0, t1, t2, t3, t4, t5, t6, t7;
                    {
#pragma clang fp contract(off)
                        t0 = ev0.x - xv0.x; o0.x = xv0.x + t0;
                        t1 = ev0.y - xv0.y; o0.y = xv0.y + t1;
                        t2 = ev0.z - xv0.z; o0.z = xv0.z + t2;
                        t3 = ev0.w - xv0.w; o0.w = xv0.w + t3;
                        t4 = ev1.x - xv1.x; o1.x = xv1.x + t4;
                        t5 = ev1.y - xv1.y; o1.y = xv1.y + t5;
                        t6 = ev1.z - xv1.z; o1.z = xv1.z + t6;
                        t7 = ev1.w - xv1.w; o1.w = xv1.w + t7;
                    }
                    float* od = out_q + (size_t)prow * 64 + kc * 32 + quad * 8;
                    *(float4*)(od)     = o0;
                    *(float4*)(od + 4) = o1;
                    s += (double)t0 * t0 + (double)t1 * t1
                       + (double)t2 * t2 + (double)t3 * t3
                       + (double)t4 * t4 + (double)t5 * t5
                       + (double)t6 * t6 + (double)t7 * t7;
                }
            }
        }
    }

#pragma unroll
    for (int off = 32; off > 0; off >>= 1)
        s += __shfl_down(s, off, 64);
    if (lane == 0) ls[wave] = s;
    __syncthreads();
    if (threadIdx.x == 0)
        partial[blockIdx.x] = ls[0] + ls[1] + ls[2] + ls[3]
                            + ls[4] + ls[5] + ls[6] + ls[7];
}

// ---------------------------------------------------------------------------
// Kernel 3: np-exact rescan of flagged points (R9-proven core) + their
// index, STE row, and loss contribution.  (Byte-identical to R4-passed.)
// ---------------------------------------------------------------------------
__global__ __launch_bounds__(256) void vq_exact(
    const float* __restrict__ x,
    const float* __restrict__ emb,
    const float* __restrict__ e2,
    const float* __restrict__ sq,
    const int* __restrict__ wl,
    const int* __restrict__ cnt,
    float* __restrict__ out_idx,
    float* __restrict__ out_q,
    double* __restrict__ partial2)
{
    const int lane = threadIdx.x & 63;
    const int gw   = blockIdx.x * 4 + (threadIdx.x >> 6);
    const int nw   = gridDim.x * 4;
    const int cv   = *cnt;

    for (int w = gw; w < cv; w += nw) {
        int p = wl[w];
        const float* xrow = x + (size_t)p * 64;
        float row[64];
#pragma unroll
        for (int i = 0; i < 16; ++i) {
            float4 v = ((const float4*)xrow)[i];
            row[4 * i + 0] = v.x; row[4 * i + 1] = v.y;
            row[4 * i + 2] = v.z; row[4 * i + 3] = v.w;
        }
        float x2 = np_sumsq64(row);

        float bd = INFINITY;
        int   bc = 0;
        for (int t = 0; t < 8; ++t) {
            int c = t * 64 + lane;
            const float* er = emb + (size_t)c * 64;
            float acc = 0.0f;
#pragma unroll
            for (int d = 0; d < 64; ++d)
                acc = fmaf(row[d], er[d], acc);
            float dist;
            {
#pragma clang fp contract(off)
                dist = ((x2 + e2[c]) - 2.0f * acc) * sq[c];
            }
            if (dist < bd) { bd = dist; bc = c; }
        }
#pragma unroll
        for (int wd = 1; wd < 64; wd <<= 1) {
            float od = __shfl_xor(bd, wd, 64);
            int   oc = __shfl_xor(bc, wd, 64);
            if (od < bd || (od == bd && oc < bc)) { bd = od; bc = oc; }
        }
        if (lane == 0) out_idx[p] = (float)bc;

        float xv = x[(size_t)p * 64 + lane];
        float qv = emb[(size_t)bc * 64 + lane];
        float t, o;
        {
#pragma clang fp contract(off)
            t = qv - xv;
            o = xv + t;
        }
        out_q[(size_t)p * 64 + lane] = o;
        double dd = (double)t * (double)t;
#pragma unroll
        for (int off = 32; off > 0; off >>= 1)
            dd += __shfl_down(dd, off, 64);
        if (lane == 0) partial2[w] = dd;
    }
}

// ---------------------------------------------------------------------------
// Kernel 4: reduce partials -> loss  (Byte-identical to R4-passed.)
// ---------------------------------------------------------------------------
__global__ __launch_bounds__(256) void vq_finalize(
    const double* __restrict__ partial,
    const double* __restrict__ partial2,
    const int* __restrict__ cnt,
    float* __restrict__ loss_out,
    int nblk, double inv_count)
{
    double s = 0.0;
    for (int i = threadIdx.x; i < nblk; i += 256) s += partial[i];
    int cv = *cnt;
    for (int w = threadIdx.x; w < cv; w += 256) s += partial2[w];
#pragma unroll
    for (int off = 32; off > 0; off >>= 1)
        s += __shfl_down(s, off, 64);
    __shared__ double ls[4];
    if ((threadIdx.x & 63) == 0) ls[threadIdx.x >> 6] = s;
    __syncthreads();
    if (threadIdx.x == 0) {
        double total = ls[0] + ls[1] + ls[2] + ls[3];
        loss_out[0] = (float)(0.25 * total * inv_count);
    }
}

// ---------------------------------------------------------------------------
extern "C" void kernel_launch(void* const* d_in, const int* in_sizes, int n_in,
                              void* d_out, int out_size, void* d_ws, size_t ws_size,
                              hipStream_t stream)
{
    const float* x   = (const float*)d_in[0];   // [N, 64]
    const float* emb = (const float*)d_in[1];   // [512, 64]
    const float* cs  = (const float*)d_in[2];   // [512]

    const int N = in_sizes[0] / D;              // 262144

    float* out      = (float*)d_out;
    float* out_q    = out;                      // [N*64]
    float* out_loss = out + (size_t)N * D;      // [1]
    float* out_idx  = out_loss + 1;             // [N]

    char* ws = (char*)d_ws;
    int*            cnt      = (int*)ws;
    float*          e2       = (float*)(ws + WS_E2);
    float*          sq       = (float*)(ws + WS_SQ);
    float2*         ets      = (float2*)(ws + WS_ETS);
    unsigned short* Bp       = (unsigned short*)(ws + WS_BP);
    int*            wl       = (int*)(ws + WS_WL);
    double*         partial  = (double*)(ws + WS_PART);
    double*         partial2 = (double*)(ws + WS_PART2);

    const int nblk_screen = N / 1024;           // 256 blocks = 1/CU

    vq_pack_prep<<<259, 256, 0, stream>>>(emb, cs, Bp, e2, sq, ets, cnt);
    vq_screen<<<nblk_screen, 512, 0, stream>>>(x, emb, ets, Bp,
                                               out_q, out_idx, wl, cnt, partial);
    vq_exact<<<512, 256, 0, stream>>>(x, emb, e2, sq, wl, cnt,
                                      out_idx, out_q, partial2);
    vq_finalize<<<1, 256, 0, stream>>>(partial, partial2, cnt, out_loss,
                                       nblk_screen, 1.0 / ((double)N * (double)D));
}